// Round 10
// baseline (320.676 us; speedup 1.0000x reference)
//
#include <hip/hip_runtime.h>
#include <math.h>

// Problem: B=4,S=2048,D=2048,E=64,K=2 -> tokens 8192, K-dim 2048, experts 64
#define NTOK 8192
#define DDIM 2048
#define NEXP 64
#define MT   16            // tokens per block
#define KSPL 2             // K split across blocks
#define KSLC (DDIM / KSPL) // 1024 k per block
#define BK   128           // k per chunk
#define NCH  (KSLC / BK)   // 8 chunks
#define XSTR 136           // x LDS row stride in halves (128 + 8 pad)
#define CSTR 68            // C-buffer row stride (floats, 16B-aligned rows)
#define NGRP (NTOK / MT)   // 512 token groups

typedef _Float16 f16x8 __attribute__((ext_vector_type(8)));
typedef float    f32x4 __attribute__((ext_vector_type(4)));

#define GATED_SZ (NTOK * NEXP)
#define IDX_OFF  GATED_SZ
#define VALS_OFF (GATED_SZ + NTOK * 2)

#define NKSTEP (DDIM / 32)            // 64 MFMA k-steps
#define NTILE  (NEXP / 16)            // 4 n-tiles
#define BFRAG_HALVES ((size_t)NKSTEP * NTILE * 64 * 8)   // 131072 halves (256KB)

// ws layout (bytes): Bh[256K] Bl[256K] P[2][512][1024] fp32 (4MB) cnt[512] int
#define P_OFF_FLOATS  (2 * BFRAG_HALVES / 2)            // 131072 floats? no:
// Bh+Bl = 524288 B = 131072 floats. P starts at float index 131072.
#define P_FLOATS_PER  (MT * NEXP)                        // 1024
#define CNT_OFF_INTS  (131072 + KSPL * NGRP * P_FLOATS_PER)  // after P

// ---------------------------------------------------------------------------
// Pack W [E=64][D=2048] into MFMA B-fragments (fp16 hi + 4096-scaled lo),
// and zero the per-token-group arrival counters (re-done every call).
// Frag (ks, nt): lane holds B[k=ks*32+(lane>>4)*8+j][n=nt*16+(lane&15)].
// Layout: Bh[((ks*4+nt)*64+lane)*8 + j]. (Verified absmax=0, rounds 6/8.)
// ---------------------------------------------------------------------------
__global__ void pack_b_kernel(const float* __restrict__ W,
                              _Float16* __restrict__ Bh,
                              _Float16* __restrict__ Bl,
                              int* __restrict__ cnt)
{
    const int tid  = blockIdx.x * blockDim.x + threadIdx.x;  // 0..16383
    if (tid < NGRP) cnt[tid] = 0;

    const int lane = tid & 63;
    const int fid  = tid >> 6;
    const int ks   = fid >> 2;
    const int nt   = fid & 3;
    const int e    = nt * 16 + (lane & 15);
    const int k    = ks * 32 + (lane >> 4) * 8;
    const float* src = W + (size_t)e * DDIM + k;

    f16x8 hi, lo;
#pragma unroll
    for (int j = 0; j < 8; ++j) {
        const float v = src[j];
        const _Float16 h = (_Float16)v;
        hi[j] = h;
        lo[j] = (_Float16)((v - (float)h) * 4096.f);
    }
    *(f16x8*)(Bh + (size_t)tid * 8) = hi;
    *(f16x8*)(Bl + (size_t)tid * 8) = lo;
}

#define BFRAG(base, kstep) \
    (*(const f16x8*)((base) + ((((size_t)(kstep)) * 4 + nt) * 64 + lane) * 8))

// ---------------------------------------------------------------------------
// Gate kernel, K-split across blocks. Grid 1024 = (grp 512) x (ks 2);
// block = 256 thr = 4 waves (one per 16-expert n-tile), 16 tokens, 1024 k.
// Small 4-wave barrier domains x 4 blocks/CU -> stalls in one domain overlap
// compute in the other three (R7-R9 showed intra-domain scheduling is
// neutral; this attacks inter-domain overlap instead).
// Cross-block combine: partial [16x64] -> ws, __threadfence, atomicAdd on
// cnt[grp]; second arrival reads partner partial and runs the epilogue.
// logits = acc_hh + 2^-12 * acc_lo (x_lo,w_lo pre-scaled by 4096).
// ---------------------------------------------------------------------------
__global__ __launch_bounds__(256, 6) void gate_kernel(
    const float* __restrict__ x,
    const _Float16* __restrict__ Bh,
    const _Float16* __restrict__ Bl,
    const float* __restrict__ noise_w,
    const float* __restrict__ noise,
    float* __restrict__ P,
    int* __restrict__ cnt,
    float* __restrict__ out)
{
    // [parity][hi/lo][MT*XSTR] staging; cbuf (16x68 fp32) aliases it after
    // the final compute barrier (staging is dead by then).
    __shared__ _Float16 pool[2][2][MT * XSTR];   // 17.4 KB
    __shared__ int sflag;
    float* cbuf = (float*)pool;                  // 4.35 KB alias

    const int tid  = threadIdx.x;
    const int lane = tid & 63;
    const int w    = __builtin_amdgcn_readfirstlane(tid >> 6);
    const int nt   = w;                          // n-tile 0..3
    const int grp  = blockIdx.x >> 1;
    const int ks   = blockIdx.x & 1;
    const int tokBase = grp * MT;

    // staging: thread covers token srow, 8 consecutive k at scol*8
    const int srow = tid >> 4;                   // 0..15
    const int scol = tid & 15;                   // 0..15
    const float* xsrc = x + (size_t)(tokBase + srow) * DDIM + ks * KSLC + scol * 8;

    const int q = lane >> 4;                     // quad 0..3
    const int m = lane & 15;
    const int abase = m * XSTR + q * 8;          // A-frag base (halves)

    f32x4 acc_hh = {0.f, 0.f, 0.f, 0.f};
    f32x4 acc_lo = {0.f, 0.f, 0.f, 0.f};

    float4 st0 = *(const float4*)(xsrc);
    float4 st1 = *(const float4*)(xsrc + 4);

    for (int c = 0; c < NCH; ++c) {
        const int p = c & 1;

        {   // convert + store staged x (hi/lo)
            f16x8 h8, l8;
            const float vv[8] = {st0.x, st0.y, st0.z, st0.w,
                                 st1.x, st1.y, st1.z, st1.w};
#pragma unroll
            for (int j = 0; j < 8; ++j) {
                const _Float16 hh = (_Float16)vv[j];
                h8[j] = hh;
                l8[j] = (_Float16)((vv[j] - (float)hh) * 4096.f);
            }
            *(f16x8*)&pool[p][0][srow * XSTR + scol * 8] = h8;
            *(f16x8*)&pool[p][1][srow * XSTR + scol * 8] = l8;
        }

        if (c + 1 < NCH) {
            st0 = *(const float4*)(xsrc + (size_t)(c + 1) * BK);
            st1 = *(const float4*)(xsrc + (size_t)(c + 1) * BK + 4);
        }

        __syncthreads();
        // single barrier/chunk safe: write(c) to parity p occurs after
        // barrier(c-1), by which time all reads(c-2) of p have retired.

        const int ksb = ks * 32 + c * 4;         // wave's k-steps this chunk
#pragma unroll
        for (int stp = 0; stp < 4; ++stp) {
            const f16x8 bh = BFRAG(Bh, ksb + stp);
            const f16x8 bl = BFRAG(Bl, ksb + stp);
            const f16x8 ah = *(const f16x8*)&pool[p][0][abase + stp * 32];
            const f16x8 al = *(const f16x8*)&pool[p][1][abase + stp * 32];
            acc_hh = __builtin_amdgcn_mfma_f32_16x16x32_f16(ah, bh, acc_hh, 0, 0, 0);
            acc_lo = __builtin_amdgcn_mfma_f32_16x16x32_f16(ah, bl, acc_lo, 0, 0, 0);
            acc_lo = __builtin_amdgcn_mfma_f32_16x16x32_f16(al, bh, acc_lo, 0, 0, 0);
        }
    }

    __syncthreads();        // all staging reads done -> cbuf alias is safe

    // combine passes -> cbuf. C/D layout: col(e)=lane&15, row(t)=q*4+r.
    {
        const int e = nt * 16 + m;
#pragma unroll
        for (int r = 0; r < 4; ++r) {
            const int t = q * 4 + r;
            cbuf[t * CSTR + e] = acc_hh[r] + acc_lo[r] * (1.f / 4096.f);
        }
    }
    __syncthreads();

    // publish partial: thread writes one float4 (coalesced)
    {
        const int t  = tid >> 4;
        const int e0 = (tid & 15) * 4;
        float* dst = P + ((size_t)ks * NGRP + grp) * P_FLOATS_PER + t * NEXP + e0;
        *(float4*)dst = *(float4*)&cbuf[t * CSTR + e0];
    }
    __threadfence();                             // release partial
    if (tid == 0)
        sflag = (atomicAdd(&cnt[grp], 1) == 1);  // device-scope
    __syncthreads();
    if (!sflag) return;                          // first arrival exits
    __threadfence();                             // acquire partner partial

    const float* partner = P + ((size_t)(ks ^ 1) * NGRP + grp) * P_FLOATS_PER;

    // Epilogue: wave w owns tokens w*4..w*4+3; lane = expert.
    const float nwv = noise_w[lane];
#pragma unroll
    for (int i = 0; i < 4; ++i) {
        const int t   = w * 4 + i;
        const int tok = tokBase + t;
        const int e   = lane;

        float v = cbuf[t * CSTR + e] + partner[t * NEXP + e]
                + noise[(size_t)tok * NEXP + e] * nwv;

        // top-1: butterfly max, lax.top_k tie-break (lower index wins)
        float m1 = v; int i1 = e;
#pragma unroll
        for (int sh = 32; sh > 0; sh >>= 1) {
            float ov = __shfl_xor(m1, sh, 64);
            int   oi = __shfl_xor(i1, sh, 64);
            if (ov > m1 || (ov == m1 && oi < i1)) { m1 = ov; i1 = oi; }
        }
        float vm = (e == i1) ? -INFINITY : v;
        float m2 = vm; int i2 = e;
#pragma unroll
        for (int sh = 32; sh > 0; sh >>= 1) {
            float ov = __shfl_xor(m2, sh, 64);
            int   oi = __shfl_xor(i2, sh, 64);
            if (ov > m2 || (ov == m2 && oi < i2)) { m2 = ov; i2 = oi; }
        }

        const float e2  = expf(m2 - m1);
        const float inv = 1.f / (1.f + e2);
        const float p1  = inv;
        const float p2  = e2 * inv;

        float gval = 0.f;
        if (e == i1) gval = p1;
        else if (e == i2) gval = p2;
        out[(size_t)tok * NEXP + e] = gval;

        if (lane == 0) {
            out[IDX_OFF  + tok * 2 + 0] = (float)i1;
            out[IDX_OFF  + tok * 2 + 1] = (float)i2;
            out[VALS_OFF + tok * 2 + 0] = m1;
            out[VALS_OFF + tok * 2 + 1] = m2;
        }
    }
}

extern "C" void kernel_launch(void* const* d_in, const int* in_sizes, int n_in,
                              void* d_out, int out_size, void* d_ws, size_t ws_size,
                              hipStream_t stream) {
    const float* x      = (const float*)d_in[0];
    const float* W      = (const float*)d_in[1];
    const float* nw     = (const float*)d_in[2];
    const float* noise  = (const float*)d_in[3];
    // d_in[4] is k==2, hardcoded
    float* out = (float*)d_out;

    _Float16* Bh = (_Float16*)d_ws;                  // 256 KB
    _Float16* Bl = Bh + BFRAG_HALVES;                // 256 KB
    float*    P  = (float*)d_ws + 131072;            // 4 MB partials
    int*      cnt = (int*)((float*)d_ws + CNT_OFF_INTS);  // 2 KB counters

    hipLaunchKernelGGL(pack_b_kernel, dim3(64), dim3(256), 0, stream,
                       W, Bh, Bl, cnt);

    hipLaunchKernelGGL(gate_kernel, dim3(NGRP * KSPL), dim3(256), 0, stream,
                       x, Bh, Bl, nw, noise, P, cnt, out);
}

// Round 11
// 132.441 us; speedup vs baseline: 2.4213x; 2.4213x over previous
//
#include <hip/hip_runtime.h>
#include <math.h>

// Problem: B=4,S=2048,D=2048,E=64,K=2 -> tokens 8192, K-dim 2048, experts 64
#define NTOK 8192
#define DDIM 2048
#define NEXP 64
#define MT   16            // tokens per block
#define KSPL 4             // K split across blocks
#define KSLC (DDIM / KSPL) // 512 k per block
#define BK   128           // k per chunk
#define NCH  (KSLC / BK)   // 4 chunks
#define XSTR 136           // x LDS row stride in halves (128 + 8 pad)
#define NGRP (NTOK / MT)   // 512 token groups

typedef _Float16 f16x8 __attribute__((ext_vector_type(8)));
typedef float    f32x4 __attribute__((ext_vector_type(4)));

#define GATED_SZ (NTOK * NEXP)
#define IDX_OFF  GATED_SZ
#define VALS_OFF (GATED_SZ + NTOK * 2)

#define NKSTEP (DDIM / 32)            // 64 MFMA k-steps
#define NTILE  (NEXP / 16)            // 4 n-tiles
#define BFRAG_HALVES ((size_t)NKSTEP * NTILE * 64 * 8)   // 131072 halves (512KB total hi+lo)

// ws layout (floats): [0,131072) Bh+Bl (as halves), then P[KSPL][NTOK][NEXP]
#define P_OFF 131072

// ---------------------------------------------------------------------------
// Pack W [E=64][D=2048] into MFMA B-fragments (fp16 hi + 4096-scaled lo).
// Frag (ks, nt): lane holds B[k=ks*32+(lane>>4)*8+j][n=nt*16+(lane&15)].
// Layout: Bh[((ks*4+nt)*64+lane)*8 + j]. (Verified absmax=0, rounds 6/8/9.)
// ---------------------------------------------------------------------------
__global__ void pack_b_kernel(const float* __restrict__ W,
                              _Float16* __restrict__ Bh,
                              _Float16* __restrict__ Bl)
{
    const int tid  = blockIdx.x * blockDim.x + threadIdx.x;  // 0..16383
    const int lane = tid & 63;
    const int fid  = tid >> 6;
    const int ks   = fid >> 2;
    const int nt   = fid & 3;
    const int e    = nt * 16 + (lane & 15);
    const int k    = ks * 32 + (lane >> 4) * 8;
    const float* src = W + (size_t)e * DDIM + k;

    f16x8 hi, lo;
#pragma unroll
    for (int j = 0; j < 8; ++j) {
        const float v = src[j];
        const _Float16 h = (_Float16)v;
        hi[j] = h;
        lo[j] = (_Float16)((v - (float)h) * 4096.f);
    }
    *(f16x8*)(Bh + (size_t)tid * 8) = hi;
    *(f16x8*)(Bl + (size_t)tid * 8) = lo;
}

#define BFRAG(base, kstep) \
    (*(const f16x8*)((base) + ((((size_t)(kstep)) * 4 + nt) * 64 + lane) * 8))

// ---------------------------------------------------------------------------
// Logits partial kernel. Grid 2048 = (grp 512) x (ks 4); block 256 thr =
// 4 waves (one per 16-expert n-tile); tile 16 tok x 512 k. 8 blocks/CU ->
// 8 independent 4-wave barrier domains per CU (stall overlap, m114).
// NO fences/atomics (round-10 lesson: device-scope fence = L2 invalidate
// storm on multi-XCD). Kernel boundary synchronizes the combine.
// Partial store straight from MFMA accumulators, coalesced.
// logits = acc_hh + 2^-12 * acc_lo (x_lo,w_lo pre-scaled by 4096).
// ---------------------------------------------------------------------------
__global__ __launch_bounds__(256, 8) void logits_kernel(
    const float* __restrict__ x,
    const _Float16* __restrict__ Bh,
    const _Float16* __restrict__ Bl,
    float* __restrict__ P)
{
    __shared__ _Float16 pool[2][2][MT * XSTR];   // [parity][hi/lo] 17.4 KB

    const int tid  = threadIdx.x;
    const int lane = tid & 63;
    const int w    = __builtin_amdgcn_readfirstlane(tid >> 6);
    const int nt   = w;                          // n-tile 0..3
    const int grp  = blockIdx.x >> 2;
    const int ks   = blockIdx.x & 3;
    const int tokBase = grp * MT;

    // staging: thread covers token srow, 8 consecutive k at scol*8
    const int srow = tid >> 4;                   // 0..15
    const int scol = tid & 15;                   // 0..15
    const float* xsrc = x + (size_t)(tokBase + srow) * DDIM + ks * KSLC + scol * 8;

    const int q = lane >> 4;                     // quad 0..3
    const int m = lane & 15;
    const int abase = m * XSTR + q * 8;          // A-frag base (halves)

    f32x4 acc_hh = {0.f, 0.f, 0.f, 0.f};
    f32x4 acc_lo = {0.f, 0.f, 0.f, 0.f};

    float4 st0 = *(const float4*)(xsrc);
    float4 st1 = *(const float4*)(xsrc + 4);

    for (int c = 0; c < NCH; ++c) {
        const int p = c & 1;

        {   // convert + store staged x (hi/lo)
            f16x8 h8, l8;
            const float vv[8] = {st0.x, st0.y, st0.z, st0.w,
                                 st1.x, st1.y, st1.z, st1.w};
#pragma unroll
            for (int j = 0; j < 8; ++j) {
                const _Float16 hh = (_Float16)vv[j];
                h8[j] = hh;
                l8[j] = (_Float16)((vv[j] - (float)hh) * 4096.f);
            }
            *(f16x8*)&pool[p][0][srow * XSTR + scol * 8] = h8;
            *(f16x8*)&pool[p][1][srow * XSTR + scol * 8] = l8;
        }

        if (c + 1 < NCH) {
            st0 = *(const float4*)(xsrc + (size_t)(c + 1) * BK);
            st1 = *(const float4*)(xsrc + (size_t)(c + 1) * BK + 4);
        }

        __syncthreads();
        // single barrier/chunk safe with parity buffers (write(c+2) occurs
        // after barrier(c+1), which orders it after all reads(c)).

        const int ksb = ks * 16 + c * 4;         // global k-step base
#pragma unroll
        for (int stp = 0; stp < 4; ++stp) {
            const f16x8 bh = BFRAG(Bh, ksb + stp);
            const f16x8 bl = BFRAG(Bl, ksb + stp);
            const f16x8 ah = *(const f16x8*)&pool[p][0][abase + stp * 32];
            const f16x8 al = *(const f16x8*)&pool[p][1][abase + stp * 32];
            acc_hh = __builtin_amdgcn_mfma_f32_16x16x32_f16(ah, bh, acc_hh, 0, 0, 0);
            acc_lo = __builtin_amdgcn_mfma_f32_16x16x32_f16(ah, bl, acc_lo, 0, 0, 0);
            acc_lo = __builtin_amdgcn_mfma_f32_16x16x32_f16(al, bh, acc_lo, 0, 0, 0);
        }
    }

    // partial store straight from accumulators, coalesced (4 x 64B segs/inst).
    // C/D layout: col(e-in-tile)=lane&15=m, row(t)=q*4+r.
    float* dst = P + ((size_t)ks * NTOK + tokBase) * NEXP + nt * 16 + m;
#pragma unroll
    for (int r = 0; r < 4; ++r)
        dst[(size_t)(q * 4 + r) * NEXP] = acc_hh[r] + acc_lo[r] * (1.f / 4096.f);
}

// ---------------------------------------------------------------------------
// Combine + gate epilogue. Grid 2048 x 256 thr; wave per token; lane = e.
// All reads coalesced (lane=e contiguous) — fixes R4/R5's strided epilogue.
// ---------------------------------------------------------------------------
__global__ __launch_bounds__(256, 8) void combine_kernel(
    const float* __restrict__ P,
    const float* __restrict__ noise_w,
    const float* __restrict__ noise,
    float* __restrict__ out)
{
    const int lane = threadIdx.x & 63;
    const int wv   = threadIdx.x >> 6;
    const int e    = lane;
    const int tok  = blockIdx.x * 4 + wv;

    const size_t off = (size_t)tok * NEXP + e;
    float v = P[off]
            + P[(size_t)1 * NTOK * NEXP + off]
            + P[(size_t)2 * NTOK * NEXP + off]
            + P[(size_t)3 * NTOK * NEXP + off]
            + noise[off] * noise_w[e];

    // top-1: butterfly max, lax.top_k tie-break (lower index wins)
    float m1 = v; int i1 = e;
#pragma unroll
    for (int sh = 32; sh > 0; sh >>= 1) {
        float ov = __shfl_xor(m1, sh, 64);
        int   oi = __shfl_xor(i1, sh, 64);
        if (ov > m1 || (ov == m1 && oi < i1)) { m1 = ov; i1 = oi; }
    }
    float vm = (e == i1) ? -INFINITY : v;
    float m2 = vm; int i2 = e;
#pragma unroll
    for (int sh = 32; sh > 0; sh >>= 1) {
        float ov = __shfl_xor(m2, sh, 64);
        int   oi = __shfl_xor(i2, sh, 64);
        if (ov > m2 || (ov == m2 && oi < i2)) { m2 = ov; i2 = oi; }
    }

    const float e2  = expf(m2 - m1);
    const float inv = 1.f / (1.f + e2);
    const float p1  = inv;
    const float p2  = e2 * inv;

    float gval = 0.f;
    if (e == i1) gval = p1;
    else if (e == i2) gval = p2;
    out[off] = gval;                             // zeros elsewhere (poisoned)

    if (lane == 0) {
        out[IDX_OFF  + tok * 2 + 0] = (float)i1;
        out[IDX_OFF  + tok * 2 + 1] = (float)i2;
        out[VALS_OFF + tok * 2 + 0] = m1;
        out[VALS_OFF + tok * 2 + 1] = m2;
    }
}

extern "C" void kernel_launch(void* const* d_in, const int* in_sizes, int n_in,
                              void* d_out, int out_size, void* d_ws, size_t ws_size,
                              hipStream_t stream) {
    const float* x      = (const float*)d_in[0];
    const float* W      = (const float*)d_in[1];
    const float* nw     = (const float*)d_in[2];
    const float* noise  = (const float*)d_in[3];
    // d_in[4] is k==2, hardcoded
    float* out = (float*)d_out;

    _Float16* Bh = (_Float16*)d_ws;                  // 256 KB
    _Float16* Bl = Bh + BFRAG_HALVES;                // 256 KB
    float*    P  = (float*)d_ws + P_OFF;             // 8 MB partials

    hipLaunchKernelGGL(pack_b_kernel, dim3(64), dim3(256), 0, stream,
                       W, Bh, Bl);

    hipLaunchKernelGGL(logits_kernel, dim3(NGRP * KSPL), dim3(256), 0, stream,
                       x, Bh, Bl, P);

    hipLaunchKernelGGL(combine_kernel, dim3(NTOK / 4), dim3(256), 0, stream,
                       P, nw, noise, out);
}